// Round 4
// baseline (79.395 us; speedup 1.0000x reference)
//
#include <hip/hip_runtime.h>
#include <hip/hip_fp16.h>

static constexpr int W56 = 56;
static constexpr int SP  = 56 * 56;   // 3136 = 49*64
static constexpr int CHN = 64;
static constexpr int NPT = 16 * SP;   // 50176 points

__device__ __forceinline__ float rfl_f(float v) {
    return __int_as_float(__builtin_amdgcn_readfirstlane(__float_as_int(v)));
}

// ---------------- K1: encode (+ one-block LUT fp32->fp16 conversion) ----------------
// grid 784 x 256. Block covers 64 consecutive points; wave 'part' encodes
// codebooks [4*part, 4*part+4). No LDS, no barrier -> pure latency-hidden gather.
__global__ __launch_bounds__(256) void k_encode(
    const float* __restrict__ x,
    const int*   __restrict__ si,
    const float* __restrict__ sv,
    const float* __restrict__ lut,
    __half2*        __restrict__ lutH2,    // ws: 8192 half2 (32 KB)
    unsigned short* __restrict__ codes)    // ws: [part][NPT]
{
    const int tid  = threadIdx.x;
    const int part = tid >> 6;
    const int lane = tid & 63;

    // one block converts the LUT to fp16 (K2 consumes it next dispatch)
    if (blockIdx.x == 0) {
        const float2* l2 = reinterpret_cast<const float2*>(lut);
        #pragma unroll
        for (int k = 0; k < 32; ++k) {
            const int idx = tid + k * 256;           // 0..8191
            lutH2[idx] = __float22half2_rn(l2[idx]);
        }
    }

    const int p  = blockIdx.x * 64 + lane;           // < 50176
    const int b  = p / SP;
    const int s  = p - b * SP;
    const int y  = s / W56;
    const int xc = s - y * W56;
    const float* __restrict__ xb = x + b * (CHN * SP);

    // branch-free gathers (16 per thread), coalesced 256B/wave each
    float v[4][4];
    #pragma unroll
    for (int c = 0; c < 4; ++c) {
        #pragma unroll
        for (int t = 0; t < 4; ++t) {
            const int cb = part * 4 + c;
            const int i  = cb * 4 + t;
            const int g  = __builtin_amdgcn_readfirstlane(si[i]) + cb * 36;
            const int ch = g / 9;
            const int k9 = g - ch * 9;
            const int ki = k9 / 3;
            const int dy = ki - 1;
            const int dx = (k9 - ki * 3) - 1;
            const int yy = y + dy, xx = xc + dx;
            const bool ok = ((unsigned)yy < (unsigned)W56) & ((unsigned)xx < (unsigned)W56);
            const int yyc = min(max(yy, 0), W56 - 1);
            const int xxc = min(max(xx, 0), W56 - 1);
            const float lv = xb[ch * SP + yyc * W56 + xxc];
            v[c][t] = ok ? lv : 0.0f;
        }
    }

    // breadth-first thresholds (wave-uniform -> scalar regs)
    float T0[4], T1[4][2], T2[4][4], T3[4][8];
    #pragma unroll
    for (int c = 0; c < 4; ++c) {
        const int base = (part * 4 + c) * 32;
        T0[c] = rfl_f(sv[base]);
        #pragma unroll
        for (int j = 0; j < 2; ++j) T1[c][j] = rfl_f(sv[base + 8  + j]);
        #pragma unroll
        for (int j = 0; j < 4; ++j) T2[c][j] = rfl_f(sv[base + 16 + j]);
        #pragma unroll
        for (int j = 0; j < 8; ++j) T3[c][j] = rfl_f(sv[base + 24 + j]);
    }

    // pure-VALU select-tree encode
    unsigned code = 0;
    #pragma unroll
    for (int c = 0; c < 4; ++c) {
        const bool b0 = v[c][0] >= T0[c];
        const float t1 = b0 ? T1[c][1] : T1[c][0];
        const bool b1 = v[c][1] >= t1;
        const float s01 = b1 ? T2[c][1] : T2[c][0];
        const float s23 = b1 ? T2[c][3] : T2[c][2];
        const bool b2 = v[c][2] >= (b0 ? s23 : s01);
        const float w0 = b2 ? T3[c][1] : T3[c][0];
        const float w1 = b2 ? T3[c][3] : T3[c][2];
        const float w2 = b2 ? T3[c][5] : T3[c][4];
        const float w3 = b2 ? T3[c][7] : T3[c][6];
        const float z0 = b1 ? w1 : w0;
        const float z1 = b1 ? w3 : w2;
        const bool b3 = v[c][3] >= (b0 ? z1 : z0);
        const int e = ((int)b0 << 3) | ((int)b1 << 2) | ((int)b2 << 1) | (int)b3;
        code |= (unsigned)e << (4 * c);
    }
    codes[part * NPT + p] = (unsigned short)code;   // coalesced 128B/wave
}

// ---------------- K2: decode ----------------
// grid 784 x 256. Wave 'q' = channel quarter; lane = point within the block's 64.
__global__ __launch_bounds__(256, 3) void k_decode(
    const __half2*        __restrict__ lutH2,
    const unsigned short* __restrict__ codes,
    const float*          __restrict__ bias,
    float*                __restrict__ out)
{
    __shared__ __half2 lutLds[256 * 36];   // row stride 36 half2 (32 used + 4 pad)

    const int tid  = threadIdx.x;
    const int q    = tid >> 6;
    const int lane = tid & 63;

    const int p = blockIdx.x * 64 + lane;
    const int b = p / SP;
    const int s = p - b * SP;

    // issue code loads first (independent of staging)
    const unsigned cd0 = codes[p];
    const unsigned cd1 = codes[NPT + p];
    const unsigned cd2 = codes[2 * NPT + p];
    const unsigned cd3 = codes[3 * NPT + p];

    // stage fp16 LUT: 2048 x 16B chunks
    const float4* src = reinterpret_cast<const float4*>(lutH2);
    #pragma unroll
    for (int i = 0; i < 8; ++i) {
        const int idx   = tid + i * 256;          // 0..2047
        const int row   = idx >> 3;               // cb*16+e
        const int chunk = idx & 7;                // 8 halves each
        *reinterpret_cast<float4*>(&lutLds[row * 36 + chunk * 4]) = src[idx];
    }
    __syncthreads();

    __half2 acc[8];
    #pragma unroll
    for (int r = 0; r < 8; ++r) acc[r] = __half2{__half(0.0f), __half(0.0f)};

    #pragma unroll
    for (int cb = 0; cb < 16; ++cb) {
        const unsigned cw = (cb < 4) ? cd0 : (cb < 8) ? cd1 : (cb < 12) ? cd2 : cd3;
        const int e = (int)((cw >> ((cb & 3) * 4)) & 15u);
        const __half2* __restrict__ row = &lutLds[(cb * 16 + e) * 36 + q * 8];
        #pragma unroll
        for (int r = 0; r < 8; ++r) acc[r] += row[r];   // v_pk_add_f16
    }

    float* __restrict__ op = out + b * (CHN * SP) + (q * 16) * SP + s;
    const float* __restrict__ bq = bias + q * 16;
    #pragma unroll
    for (int r = 0; r < 8; ++r) {
        const float2 f = __half22float2(acc[r]);
        op[(2 * r)     * SP] = f.x + bq[2 * r];
        op[(2 * r + 1) * SP] = f.y + bq[2 * r + 1];
    }
}

extern "C" void kernel_launch(void* const* d_in, const int* in_sizes, int n_in,
                              void* d_out, int out_size, void* d_ws, size_t ws_size,
                              hipStream_t stream) {
    const float* x  = (const float*)d_in[0];
    const int*   si = (const int*)  d_in[1];
    const float* sv = (const float*)d_in[2];
    const float* lt = (const float*)d_in[3];
    const float* bs = (const float*)d_in[4];
    float* o = (float*)d_out;

    __half2*        lutH2 = (__half2*)d_ws;                              // 32 KB
    unsigned short* codes = (unsigned short*)((char*)d_ws + 32768);      // 4*50176*2 B

    k_encode<<<dim3(784), dim3(256), 0, stream>>>(x, si, sv, lt, lutH2, codes);
    k_decode<<<dim3(784), dim3(256), 0, stream>>>(lutH2, codes, bs, o);
}

// Round 5
// 77.430 us; speedup vs baseline: 1.0254x; 1.0254x over previous
//
#include <hip/hip_runtime.h>
#include <hip/hip_fp16.h>

static constexpr int W56 = 56;
static constexpr int SP  = 56 * 56;   // 3136 = 49*64
static constexpr int CHN = 64;

__device__ __forceinline__ float rfl_f(float v) {
    return __int_as_float(__builtin_amdgcn_readfirstlane(__float_as_int(v)));
}

// Single fused dispatch. grid = 784 blocks (16 b * 49 point-groups), block = 256.
// Block covers 64 consecutive points x all 64 channels.
// Phase 1: wave 'part' encodes codebooks [4*part,4*part+4) for the 64 points
//          (branch-free gathers -> SGPR thresholds -> VALU select tree).
//          Meanwhile all threads stage the fp32 LUT into LDS as fp16.
// Phase 2: wave 'part' = channel quarter; sums 16 fp16 LUT rows + fp32 bias.
__global__ __launch_bounds__(256, 3) void maddness_fused(
    const float* __restrict__ x,
    const int*   __restrict__ si,
    const float* __restrict__ sv,
    const float* __restrict__ lut,
    const float* __restrict__ bias,
    float*       __restrict__ out)
{
    __shared__ __half2        lutLds[256 * 36];  // row stride 36 half2 (32 used + 4 pad): e vs e+8 alias only = free 2-way
    __shared__ unsigned short codes[256];

    const int tid  = threadIdx.x;
    const int part = tid >> 6;
    const int lane = tid & 63;

    const int p  = blockIdx.x * 64 + lane;       // < 50176 exactly
    const int b  = p / SP;
    const int s  = p - b * SP;
    const int y  = s / W56;
    const int xc = s - y * W56;
    const float* __restrict__ xb = x + b * (CHN * SP);

    // ---- gathers FIRST (longest latency; branch-free, coalesced 256B/wave) ----
    float v[4][4];
    #pragma unroll
    for (int c = 0; c < 4; ++c) {
        #pragma unroll
        for (int t = 0; t < 4; ++t) {
            const int cb = part * 4 + c;
            const int i  = cb * 4 + t;
            const int g  = __builtin_amdgcn_readfirstlane(si[i]) + cb * 36;
            const int ch = g / 9;
            const int k9 = g - ch * 9;
            const int ki = k9 / 3;
            const int dy = ki - 1;
            const int dx = (k9 - ki * 3) - 1;
            const int yy = y + dy, xx = xc + dx;
            const bool ok = ((unsigned)yy < (unsigned)W56) & ((unsigned)xx < (unsigned)W56);
            const int yyc = min(max(yy, 0), W56 - 1);
            const int xxc = min(max(xx, 0), W56 - 1);
            const float lv = xb[ch * SP + yyc * W56 + xxc];
            v[c][t] = ok ? lv : 0.0f;
        }
    }

    // ---- LUT staging: fp32 -> fp16, 16 global float4 loads + 8 ds_write_b128 ----
    const float4* lut4 = reinterpret_cast<const float4*>(lut);
    #pragma unroll
    for (int i = 0; i < 8; ++i) {
        const int idx = tid + i * 256;           // 0..2047: one 16B fp16 chunk (8 halves)
        const int row = idx >> 3;                // cb*16+e
        const int ck  = idx & 7;
        const float4 f0 = lut4[idx * 2];
        const float4 f1 = lut4[idx * 2 + 1];
        __half2 h[4];
        h[0] = __float22half2_rn(make_float2(f0.x, f0.y));
        h[1] = __float22half2_rn(make_float2(f0.z, f0.w));
        h[2] = __float22half2_rn(make_float2(f1.x, f1.y));
        h[3] = __float22half2_rn(make_float2(f1.z, f1.w));
        *reinterpret_cast<float4*>(&lutLds[row * 36 + ck * 4]) = *reinterpret_cast<const float4*>(h);
    }

    // ---- breadth-first thresholds (wave-uniform -> scalar regs) ----
    float T0[4], T1[4][2], T2[4][4], T3[4][8];
    #pragma unroll
    for (int c = 0; c < 4; ++c) {
        const int base = (part * 4 + c) * 32;
        T0[c] = rfl_f(sv[base]);
        #pragma unroll
        for (int j = 0; j < 2; ++j) T1[c][j] = rfl_f(sv[base + 8  + j]);
        #pragma unroll
        for (int j = 0; j < 4; ++j) T2[c][j] = rfl_f(sv[base + 16 + j]);
        #pragma unroll
        for (int j = 0; j < 8; ++j) T3[c][j] = rfl_f(sv[base + 24 + j]);
    }

    // ---- pure-VALU select-tree encode ----
    unsigned code = 0;
    #pragma unroll
    for (int c = 0; c < 4; ++c) {
        const bool b0 = v[c][0] >= T0[c];
        const float t1 = b0 ? T1[c][1] : T1[c][0];
        const bool b1 = v[c][1] >= t1;
        const float s01 = b1 ? T2[c][1] : T2[c][0];
        const float s23 = b1 ? T2[c][3] : T2[c][2];
        const bool b2 = v[c][2] >= (b0 ? s23 : s01);
        const float w0 = b2 ? T3[c][1] : T3[c][0];
        const float w1 = b2 ? T3[c][3] : T3[c][2];
        const float w2 = b2 ? T3[c][5] : T3[c][4];
        const float w3 = b2 ? T3[c][7] : T3[c][6];
        const float z0 = b1 ? w1 : w0;
        const float z1 = b1 ? w3 : w2;
        const bool b3 = v[c][3] >= (b0 ? z1 : z0);
        const int e = ((int)b0 << 3) | ((int)b1 << 2) | ((int)b2 << 1) | (int)b3;
        code |= (unsigned)e << (4 * c);
    }
    codes[part * 64 + lane] = (unsigned short)code;
    __syncthreads();

    // ---- phase 2: decode. wave 'part' = quarter q ----
    const int q = part;
    const unsigned cd0 = codes[lane];
    const unsigned cd1 = codes[64 + lane];
    const unsigned cd2 = codes[128 + lane];
    const unsigned cd3 = codes[192 + lane];

    __half2 acc[8];
    #pragma unroll
    for (int r = 0; r < 8; ++r) acc[r] = __half2{__half(0.0f), __half(0.0f)};

    #pragma unroll
    for (int cb = 0; cb < 16; ++cb) {
        const unsigned cw = (cb < 4) ? cd0 : (cb < 8) ? cd1 : (cb < 12) ? cd2 : cd3;
        const int e = (int)((cw >> ((cb & 3) * 4)) & 15u);
        const __half2* __restrict__ row = &lutLds[(cb * 16 + e) * 36 + q * 8];
        #pragma unroll
        for (int r = 0; r < 8; ++r) acc[r] += row[r];   // 2x ds_read_b128 + v_pk_add_f16
    }

    float* __restrict__ op = out + b * (CHN * SP) + (q * 16) * SP + s;
    const float* __restrict__ bq = bias + q * 16;
    #pragma unroll
    for (int r = 0; r < 8; ++r) {
        const float2 f = __half22float2(acc[r]);
        op[(2 * r)     * SP] = f.x + bq[2 * r];
        op[(2 * r + 1) * SP] = f.y + bq[2 * r + 1];
    }
}

extern "C" void kernel_launch(void* const* d_in, const int* in_sizes, int n_in,
                              void* d_out, int out_size, void* d_ws, size_t ws_size,
                              hipStream_t stream) {
    const float* x  = (const float*)d_in[0];
    const int*   si = (const int*)  d_in[1];
    const float* sv = (const float*)d_in[2];
    const float* lt = (const float*)d_in[3];
    const float* bs = (const float*)d_in[4];
    float* o = (float*)d_out;

    maddness_fused<<<dim3(784), dim3(256), 0, stream>>>(x, si, sv, lt, bs, o);
}